// Round 1
// baseline (9188.281 us; speedup 1.0000x reference)
//
#include <hip/hip_runtime.h>
#include <math.h>

#define BATCH   32
#define NNODE   325
#define T_HIST  12
#define T_PRED  12
#define H       256
#define G4      1024          // 4*H
#define ROWS    (BATCH*NNODE) // 10400

// ---------------------------------------------------------------------------
// Weight preparation kernels
// ---------------------------------------------------------------------------

// w: [nblk*cin, H] row-major.  out[c][h] = sum_k w[k*cin + c][h]
__global__ void collapse_kernel(const float* __restrict__ w, float* __restrict__ out,
                                int cin, int nblk) {
    int idx = blockIdx.x * blockDim.x + threadIdx.x;
    int total = cin * H;
    if (idx >= total) return;
    int c = idx / H, h = idx % H;
    float s = 0.f;
    for (int k = 0; k < nblk; ++k) s += w[(size_t)(k * cin + c) * H + h];
    out[idx] = s;
}

// out[out_row_off + c][r] = in[r][c]   (in: [in_rows, in_cols], both mult of 32)
__global__ void transpose_kernel(const float* __restrict__ in, float* __restrict__ out,
                                 int in_rows, int in_cols, int out_ld, int out_row_off) {
    __shared__ float tile[32][33];
    int r0 = blockIdx.y * 32, c0 = blockIdx.x * 32;
    int tx = threadIdx.x & 31, ty = threadIdx.x >> 5;
#pragma unroll
    for (int i = 0; i < 32; i += 8)
        tile[ty + i][tx] = in[(size_t)(r0 + ty + i) * in_cols + c0 + tx];
    __syncthreads();
#pragma unroll
    for (int i = 0; i < 32; i += 8)
        out[(size_t)(out_row_off + c0 + ty + i) * out_ld + r0 + tx] = tile[tx][ty + i];
}

__global__ void add_vec_kernel(const float* __restrict__ a, const float* __restrict__ b,
                               float* __restrict__ o, int n) {
    int i = blockIdx.x * blockDim.x + threadIdx.x;
    if (i < n) o[i] = a[i] + b[i];
}

// ---------------------------------------------------------------------------
// Tiled SGEMM: C[M,N] = act( [A1|A2][M,K] @ B[K,N] + bias )
// A1 holds k in [0,K1) (lda=K1), A2 holds k in [K1,K) (lda=K-K1). A2 may be null.
// Micro-tile is split in 2 groups of 4 (rows/cols) for conflict-light float4 LDS reads.
// ---------------------------------------------------------------------------
template <int BM, int BN, int TM, int TN>
__global__ __launch_bounds__(256) void gemm_kernel(
    const float* __restrict__ A1, const float* __restrict__ A2, int K1,
    const float* __restrict__ B, const float* __restrict__ bias,
    float* __restrict__ C, int M, int N, int K, int doRelu)
{
    constexpr int BKt = 16;
    constexpr int TX = BN / TN;   // threads along n
    constexpr int TY = BM / TM;   // threads along m
    static_assert(TX * TY == 256, "256 threads");
    __shared__ float As[BKt][BM];
    __shared__ float Bs[BKt][BN];

    const int tid = threadIdx.x;
    const int tx = tid % TX, ty = tid / TX;
    const int bm = blockIdx.x * BM, bn = blockIdx.y * BN;

    float acc[TM][TN];
#pragma unroll
    for (int i = 0; i < TM; ++i)
#pragma unroll
        for (int j = 0; j < TN; ++j) acc[i][j] = 0.f;

    for (int k0 = 0; k0 < K; k0 += BKt) {
        const float* Aseg = (k0 < K1) ? A1 : A2;
        const int lda   = (k0 < K1) ? K1 : (K - K1);
        const int kbase = (k0 < K1) ? k0 : (k0 - K1);
        // ---- load A tile (BM x 16) ----
#pragma unroll
        for (int i = 0; i < BM / 64; ++i) {
            int idx = tid + i * 256;          // each idx loads one float4
            int m = idx >> 2;
            int kk = (idx & 3) * 4;
            int gm = bm + m;
            float4 v = make_float4(0.f, 0.f, 0.f, 0.f);
            if (gm < M) v = *(const float4*)&Aseg[(size_t)gm * lda + kbase + kk];
            As[kk + 0][m] = v.x; As[kk + 1][m] = v.y;
            As[kk + 2][m] = v.z; As[kk + 3][m] = v.w;
        }
        // ---- load B tile (16 x BN) ----
#pragma unroll
        for (int i = 0; i < BN / 64; ++i) {
            int idx = tid + i * 256;
            int kk = idx / (BN / 4);
            int nn = (idx % (BN / 4)) * 4;
            *(float4*)&Bs[kk][nn] = *(const float4*)&B[(size_t)(k0 + kk) * N + bn + nn];
        }
        __syncthreads();
        // ---- FMA ----
#pragma unroll
        for (int k = 0; k < BKt; ++k) {
            float a[TM], b[TN];
#pragma unroll
            for (int g = 0; g < TM / 4; ++g) {
                float4 v = *(const float4*)&As[k][g * (BM / 2) + ty * 4];
                a[4 * g + 0] = v.x; a[4 * g + 1] = v.y; a[4 * g + 2] = v.z; a[4 * g + 3] = v.w;
            }
#pragma unroll
            for (int g = 0; g < TN / 4; ++g) {
                float4 v = *(const float4*)&Bs[k][g * (BN / 2) + tx * 4];
                b[4 * g + 0] = v.x; b[4 * g + 1] = v.y; b[4 * g + 2] = v.z; b[4 * g + 3] = v.w;
            }
#pragma unroll
            for (int i = 0; i < TM; ++i)
#pragma unroll
                for (int j = 0; j < TN; ++j) acc[i][j] += a[i] * b[j];
        }
        __syncthreads();
    }
    // ---- epilogue ----
#pragma unroll
    for (int i = 0; i < TM; ++i) {
        int gm = bm + (i / 4) * (BM / 2) + ty * 4 + (i & 3);
        if (gm >= M) continue;
#pragma unroll
        for (int g = 0; g < TN / 4; ++g) {
            int gn = bn + g * (BN / 2) + tx * 4;
            float4 v;
            float bz[4] = {0.f, 0.f, 0.f, 0.f};
            if (bias) { float4 bb = *(const float4*)&bias[gn]; bz[0]=bb.x; bz[1]=bb.y; bz[2]=bb.z; bz[3]=bb.w; }
            v.x = acc[i][4 * g + 0] + bz[0];
            v.y = acc[i][4 * g + 1] + bz[1];
            v.z = acc[i][4 * g + 2] + bz[2];
            v.w = acc[i][4 * g + 3] + bz[3];
            if (doRelu) {
                v.x = fmaxf(v.x, 0.f); v.y = fmaxf(v.y, 0.f);
                v.z = fmaxf(v.z, 0.f); v.w = fmaxf(v.w, 0.f);
            }
            *(float4*)&C[(size_t)gm * N + gn] = v;
        }
    }
}

// ---------------------------------------------------------------------------
// Elementwise kernels
// ---------------------------------------------------------------------------

// encoder pre layer 0: out[r][h] = relu(in_t[r][0]*w[0][h] + in_t[r][1]*w[1][h] + b[h])
__global__ void enc_pre0_kernel(const float* __restrict__ inp, const float* __restrict__ w,
                                const float* __restrict__ b, float* __restrict__ out, int t) {
    int idx = blockIdx.x * blockDim.x + threadIdx.x;
    if (idx >= ROWS * H) return;
    int r = idx / H, h = idx % H;
    int bb = r / NNODE, n = r % NNODE;
    const float* ip = inp + (((size_t)bb * T_HIST + t) * NNODE + n) * 2;
    float v = ip[0] * w[h] + ip[1] * w[H + h] + b[h];
    out[idx] = fmaxf(v, 0.f);
}

// decoder pre layer 0: out[r][h] = relu(y[r]*w[h] + b[h])
__global__ void dec_pre0_kernel(const float* __restrict__ y, const float* __restrict__ w,
                                const float* __restrict__ b, float* __restrict__ out) {
    int idx = blockIdx.x * blockDim.x + threadIdx.x;
    if (idx >= ROWS * H) return;
    int r = idx / H, h = idx % H;
    float v = y[r] * w[h] + b[h];
    out[idx] = fmaxf(v, 0.f);
}

// LSTM cell: gates [ROWS, 4H] (i,f,g,o), h/c updated in place
__global__ void lstm_cell_kernel(const float* __restrict__ gates,
                                 float* __restrict__ h, float* __restrict__ c) {
    int idx = blockIdx.x * blockDim.x + threadIdx.x;
    if (idx >= ROWS * H) return;
    int r = idx / H, j = idx % H;
    const float* g = gates + (size_t)r * G4 + j;
    float ig = g[0], fg = g[H], gg = g[2 * H], og = g[3 * H];
    float si = 1.f / (1.f + expf(-ig));
    float sf = 1.f / (1.f + expf(-fg));
    float so = 1.f / (1.f + expf(-og));
    float tg = tanhf(gg);
    float cn = sf * c[idx] + si * tg;
    float hn = so * tanhf(cn);
    c[idx] = cn;
    h[idx] = hn;
}

// projection: y[r] = x[r,:]·pw + pb ; also scatter into d_out[b][t][n]
__global__ void proj_kernel(const float* __restrict__ x, const float* __restrict__ pw,
                            const float* __restrict__ pb, float* __restrict__ y,
                            float* __restrict__ out, int t) {
    int wid = threadIdx.x >> 6, lane = threadIdx.x & 63;
    int r = blockIdx.x * 4 + wid;
    if (r >= ROWS) return;
    const float* xr = x + (size_t)r * H;
    float s = 0.f;
#pragma unroll
    for (int i = 0; i < H / 64; ++i) s += xr[lane + i * 64] * pw[lane + i * 64];
#pragma unroll
    for (int off = 32; off > 0; off >>= 1) s += __shfl_down(s, off, 64);
    if (lane == 0) {
        float v = s + pb[0];
        y[r] = v;
        int bb = r / NNODE, n = r % NNODE;
        out[((size_t)bb * T_PRED + t) * NNODE + n] = v;
    }
}

// ---------------------------------------------------------------------------
// Host-side launch helpers
// ---------------------------------------------------------------------------
static inline void gemm_big(const float* A1, const float* A2, int K1, const float* B,
                            const float* bias, float* C, int M, int N, int K, int relu,
                            hipStream_t s) {
    dim3 grid((M + 127) / 128, N / 128);
    gemm_kernel<128, 128, 8, 8><<<grid, 256, 0, s>>>(A1, A2, K1, B, bias, C, M, N, K, relu);
}
static inline void gemm_small(const float* A1, const float* B, const float* bias, float* C,
                              int M, int N, int K, int relu, hipStream_t s) {
    dim3 grid((M + 63) / 64, N / 64);
    gemm_kernel<64, 64, 4, 4><<<grid, 256, 0, s>>>(A1, nullptr, K, B, bias, C, M, N, K, relu);
}

extern "C" void kernel_launch(void* const* d_in, const int* in_sizes, int n_in,
                              void* d_out, int out_size, void* d_ws, size_t ws_size,
                              hipStream_t stream) {
    (void)in_sizes; (void)n_in; (void)out_size; (void)ws_size;

    const float* inputs      = (const float*)d_in[0];
    // d_in[1..7]: vertexes + arcs MLP — dead code (supports are identity), skipped.
    const float* enc_pre_w0  = (const float*)d_in[8];
    const float* enc_pre_b0  = (const float*)d_in[9];
    const float* enc_pre_w1  = (const float*)d_in[10];
    const float* enc_pre_b1  = (const float*)d_in[11];
    const float* enc_wih     = (const float*)d_in[12];
    const float* enc_whh     = (const float*)d_in[13];
    const float* enc_bih     = (const float*)d_in[14];
    const float* enc_bhh     = (const float*)d_in[15];
    const float* dec_pre_w0  = (const float*)d_in[16];
    const float* dec_pre_b0  = (const float*)d_in[17];
    const float* dec_pre_w1  = (const float*)d_in[18];
    const float* dec_pre_b1  = (const float*)d_in[19];
    const float* dec_wih     = (const float*)d_in[20];
    const float* dec_whh     = (const float*)d_in[21];
    const float* dec_bih     = (const float*)d_in[22];
    const float* dec_bhh     = (const float*)d_in[23];
    const float* dec_post_w0 = (const float*)d_in[24];
    const float* dec_post_b0 = (const float*)d_in[25];
    const float* dec_post_w1 = (const float*)d_in[26];
    const float* dec_post_b1 = (const float*)d_in[27];
    const float* proj_w      = (const float*)d_in[28];
    const float* proj_b      = (const float*)d_in[29];
    float* out = (float*)d_out;

    // ---- workspace layout (floats) ----
    float* ws = (float*)d_ws;
    size_t off = 0;
    auto alloc = [&](size_t n) { float* p = ws + off; off += n; return p; };
    float* encW0eff   = alloc(2 * H);
    float* encW1eff   = alloc(H * H);
    float* decPre0eff = alloc(H);
    float* decPre1eff = alloc(H * H);
    float* decPost0eff= alloc(H * H);
    float* decPost1eff= alloc(H * H);
    float* encB0T = alloc(512 * G4);
    float* encB1T = alloc(512 * G4);
    float* decB0T = alloc(512 * G4);
    float* decB1T = alloc(512 * G4);
    float* encBias0 = alloc(G4);
    float* encBias1 = alloc(G4);
    float* decBias0 = alloc(G4);
    float* decBias1 = alloc(G4);
    float* h0 = alloc((size_t)ROWS * H);
    float* c0 = alloc((size_t)ROWS * H);
    float* h1 = alloc((size_t)ROWS * H);
    float* c1 = alloc((size_t)ROWS * H);
    float* xa = alloc((size_t)ROWS * H);
    float* xb = alloc((size_t)ROWS * H);
    float* gates = alloc((size_t)ROWS * G4);
    float* y  = alloc(ROWS);

    const int EW = 256;
    const size_t LOFF = (size_t)G4 * H;  // per-layer weight offset 262144

    // ---- weight prep ----
    collapse_kernel<<<(2 * H + EW - 1) / EW, EW, 0, stream>>>(enc_pre_w0, encW0eff, 2, 5);
    collapse_kernel<<<(H * H + EW - 1) / EW, EW, 0, stream>>>(enc_pre_w1, encW1eff, H, 5);
    collapse_kernel<<<(H + EW - 1) / EW, EW, 0, stream>>>(dec_pre_w0, decPre0eff, 1, 5);
    collapse_kernel<<<(H * H + EW - 1) / EW, EW, 0, stream>>>(dec_pre_w1, decPre1eff, H, 5);
    collapse_kernel<<<(H * H + EW - 1) / EW, EW, 0, stream>>>(dec_post_w0, decPost0eff, H, 5);
    collapse_kernel<<<(H * H + EW - 1) / EW, EW, 0, stream>>>(dec_post_w1, decPost1eff, H, 5);

    dim3 tgrid(H / 32, G4 / 32);
    transpose_kernel<<<tgrid, 256, 0, stream>>>(enc_wih,        encB0T, G4, H, G4, 0);
    transpose_kernel<<<tgrid, 256, 0, stream>>>(enc_whh,        encB0T, G4, H, G4, H);
    transpose_kernel<<<tgrid, 256, 0, stream>>>(enc_wih + LOFF, encB1T, G4, H, G4, 0);
    transpose_kernel<<<tgrid, 256, 0, stream>>>(enc_whh + LOFF, encB1T, G4, H, G4, H);
    transpose_kernel<<<tgrid, 256, 0, stream>>>(dec_wih,        decB0T, G4, H, G4, 0);
    transpose_kernel<<<tgrid, 256, 0, stream>>>(dec_whh,        decB0T, G4, H, G4, H);
    transpose_kernel<<<tgrid, 256, 0, stream>>>(dec_wih + LOFF, decB1T, G4, H, G4, 0);
    transpose_kernel<<<tgrid, 256, 0, stream>>>(dec_whh + LOFF, decB1T, G4, H, G4, H);

    add_vec_kernel<<<(G4 + EW - 1) / EW, EW, 0, stream>>>(enc_bih,        enc_bhh,        encBias0, G4);
    add_vec_kernel<<<(G4 + EW - 1) / EW, EW, 0, stream>>>(enc_bih + G4,   enc_bhh + G4,   encBias1, G4);
    add_vec_kernel<<<(G4 + EW - 1) / EW, EW, 0, stream>>>(dec_bih,        dec_bhh,        decBias0, G4);
    add_vec_kernel<<<(G4 + EW - 1) / EW, EW, 0, stream>>>(dec_bih + G4,   dec_bhh + G4,   decBias1, G4);

    // ---- init state ----
    hipMemsetAsync(h0, 0, (size_t)ROWS * H * sizeof(float), stream);
    hipMemsetAsync(c0, 0, (size_t)ROWS * H * sizeof(float), stream);
    hipMemsetAsync(h1, 0, (size_t)ROWS * H * sizeof(float), stream);
    hipMemsetAsync(c1, 0, (size_t)ROWS * H * sizeof(float), stream);

    const int EB = (ROWS * H + EW - 1) / EW;

    // ---- encoder ----
    for (int t = 0; t < T_HIST; ++t) {
        enc_pre0_kernel<<<EB, EW, 0, stream>>>(inputs, encW0eff, enc_pre_b0, xa, t);
        gemm_small(xa, encW1eff, enc_pre_b1, xb, ROWS, H, H, 1, stream);
        gemm_big(xb, h0, H, encB0T, encBias0, gates, ROWS, G4, 2 * H, 0, stream);
        lstm_cell_kernel<<<EB, EW, 0, stream>>>(gates, h0, c0);
        gemm_big(h0, h1, H, encB1T, encBias1, gates, ROWS, G4, 2 * H, 0, stream);
        lstm_cell_kernel<<<EB, EW, 0, stream>>>(gates, h1, c1);
    }

    // ---- decoder ----
    hipMemsetAsync(y, 0, ROWS * sizeof(float), stream);
    for (int t = 0; t < T_PRED; ++t) {
        dec_pre0_kernel<<<EB, EW, 0, stream>>>(y, decPre0eff, dec_pre_b0, xa);
        gemm_small(xa, decPre1eff, dec_pre_b1, xb, ROWS, H, H, 1, stream);
        gemm_big(xb, h0, H, decB0T, decBias0, gates, ROWS, G4, 2 * H, 0, stream);
        lstm_cell_kernel<<<EB, EW, 0, stream>>>(gates, h0, c0);
        gemm_big(h0, h1, H, decB1T, decBias1, gates, ROWS, G4, 2 * H, 0, stream);
        lstm_cell_kernel<<<EB, EW, 0, stream>>>(gates, h1, c1);
        gemm_small(h1, decPost0eff, dec_post_b0, xa, ROWS, H, H, 1, stream);
        gemm_small(xa, decPost1eff, dec_post_b1, xb, ROWS, H, H, 1, stream);
        proj_kernel<<<(ROWS + 3) / 4, 256, 0, stream>>>(xb, proj_w, proj_b, y, out, t);
    }
}

// Round 2
// 4094.134 us; speedup vs baseline: 2.2443x; 2.2443x over previous
//
#include <hip/hip_runtime.h>
#include <math.h>

#define BATCH   32
#define NNODE   325
#define T_HIST  12
#define T_PRED  12
#define H       256
#define G4      1024          // 4*H
#define ROWS    (BATCH*NNODE) // 10400
#define MPAD    10496         // 82*128

typedef __attribute__((ext_vector_type(8))) short bf16x8;
typedef __attribute__((ext_vector_type(4))) float f32x4;
typedef unsigned short ushort_t;
typedef unsigned int uint_t;

// global -> LDS async 16B copy; gp per-lane, sp must be wave-uniform (HW adds lane*16)
#define GLL16(gp, sp) __builtin_amdgcn_global_load_lds( \
    (const __attribute__((address_space(1))) void*)(gp), \
    (__attribute__((address_space(3))) void*)(sp), 16, 0, 0)

__device__ inline float bf2f(ushort_t u) { return __uint_as_float(((uint_t)u) << 16); }

// round-to-nearest-even split: v ~= hi + lo (both bf16), residual ~ 2^-18 |v|
__device__ inline void split2(float v, ushort_t& h, ushort_t& l) {
    uint_t b = __float_as_uint(v);
    uint_t hb = (b + 0x7fffu + ((b >> 16) & 1u)) & 0xffff0000u;
    h = (ushort_t)(hb >> 16);
    float r = v - __uint_as_float(hb);
    uint_t rb = __float_as_uint(r);
    l = (ushort_t)((rb + 0x7fffu + ((rb >> 16) & 1u)) >> 16);
}

// ---------------------------------------------------------------------------
// Weight prep
// ---------------------------------------------------------------------------

// w: [nblk*cin, H]. out[c][h] = sum_k w[k*cin + c][h]   (fp32 effective weight)
__global__ void collapse_kernel(const float* __restrict__ w, float* __restrict__ out,
                                int cin, int nblk) {
    int idx = blockIdx.x * blockDim.x + threadIdx.x;
    if (idx >= cin * H) return;
    int c = idx / H, h = idx % H;
    float s = 0.f;
    for (int k = 0; k < nblk; ++k) s += w[(size_t)(k * cin + c) * H + h];
    out[idx] = s;
}

__global__ void add_vec_kernel(const float* __restrict__ a, const float* __restrict__ b,
                               float* __restrict__ o, int n) {
    int i = blockIdx.x * blockDim.x + threadIdx.x;
    if (i < n) o[i] = a[i] + b[i];
}

// Big-GEMM weight pack: logical B[k][g] (K=512: k<256 from wih[g][k], else whh[g][k-256])
// -> Bpk[kg][g][j] = B[kg*8+j][g], split hi/lo bf16.  64*1024 threads.
__global__ void pack_big_kernel(const float* __restrict__ wih, const float* __restrict__ whh,
                                ushort_t* __restrict__ Bh, ushort_t* __restrict__ Bl) {
    int idx = blockIdx.x * blockDim.x + threadIdx.x;
    if (idx >= 64 * G4) return;
    int kg = idx >> 10, g = idx & 1023;
    const float* src = (kg < 32 ? wih : whh) + (size_t)g * H + (kg & 31) * 8;
    ushort_t h8[8], l8[8];
#pragma unroll
    for (int j = 0; j < 8; ++j) split2(src[j], h8[j], l8[j]);
#pragma unroll
    for (int j = 0; j < 8; ++j) { Bh[(size_t)idx * 8 + j] = h8[j]; Bl[(size_t)idx * 8 + j] = l8[j]; }
}

// Small-GEMM weight: collapse 5 K-blocks of w [5*256,256] then pack [32][256][8] hi/lo.
__global__ void pack_small_kernel(const float* __restrict__ w,
                                  ushort_t* __restrict__ Bh, ushort_t* __restrict__ Bl) {
    int idx = blockIdx.x * blockDim.x + threadIdx.x;
    if (idx >= 32 * H) return;
    int kg = idx >> 8, n = idx & 255;
#pragma unroll
    for (int j = 0; j < 8; ++j) {
        int k = kg * 8 + j;
        float s = 0.f;
        for (int blk = 0; blk < 5; ++blk) s += w[(size_t)(blk * H + k) * H + n];
        ushort_t hh, ll; split2(s, hh, ll);
        Bh[(size_t)idx * 8 + j] = hh; Bl[(size_t)idx * 8 + j] = ll;
    }
}

// ---------------------------------------------------------------------------
// Split-bf16 MFMA GEMM.  C[M=10496, N] = act( [A1|A2] @ B + bias )
// A arrays: bf16 hi/lo pairs, row stride 256.  B: packed [K/8][N][8] hi/lo.
// MODE 0: C fp32 (+bias).  MODE 1: relu(+bias) -> split bf16 pair out (stride N).
// ---------------------------------------------------------------------------
template <int MODE>
__global__ __launch_bounds__(256, 2) void gemm_bf16s_kernel(
    const ushort_t* __restrict__ A1h, const ushort_t* __restrict__ A1l,
    const ushort_t* __restrict__ A2h, const ushort_t* __restrict__ A2l, int K1,
    const ushort_t* __restrict__ Bh, const ushort_t* __restrict__ Bl,
    const float* __restrict__ bias,
    float* __restrict__ Cf, ushort_t* __restrict__ Ch, ushort_t* __restrict__ Cl,
    int N, int K, int nbx, int doSwz)
{
    __shared__ __align__(16) ushort_t AsH[8192], AsL[8192], BsH[8192], BsL[8192]; // 16KB each

    int bid = blockIdx.x;
    if (doSwz) { int cpx = gridDim.x >> 3; bid = (bid & 7) * cpx + (bid >> 3); }
    const int bm = (bid / nbx) * 128, bn = (bid % nbx) * 128;
    const int tid = threadIdx.x, lane = tid & 63;
    const int wm = (tid >> 7) & 1, wn = (tid >> 6) & 1;
    const int l15 = lane & 15, lk = lane >> 4;

    f32x4 acc[4][4] = {};

    const int nsteps = K >> 6;
    for (int step = 0; step < nsteps; ++step) {
        const int k0 = step * 64;
        const ushort_t* Ah; const ushort_t* Al; int koff;
        if (k0 < K1) { Ah = A1h; Al = A1l; koff = k0; }
        else         { Ah = A2h; Al = A2l; koff = k0 - K1; }
        __syncthreads();
#pragma unroll
        for (int i = 0; i < 4; ++i) {
            int cw = (tid & ~63) + i * 256;     // wave-uniform chunk base
            int cl = cw + lane;                 // this lane's chunk
            int kgl = cl >> 7, mn = cl & 127;
            size_t ga = (size_t)(bm + mn) * 256 + koff + kgl * 8;        // bf16 elems
            size_t gb = ((size_t)((k0 >> 3) + kgl) * N + bn + mn) * 8;   // bf16 elems
            GLL16(Ah + ga, &AsH[(size_t)cw * 8]);
            GLL16(Al + ga, &AsL[(size_t)cw * 8]);
            GLL16(Bh + gb, &BsH[(size_t)cw * 8]);
            GLL16(Bl + gb, &BsL[(size_t)cw * 8]);
        }
        __syncthreads();
#pragma unroll
        for (int s = 0; s < 2; ++s) {
            bf16x8 ah[4], al[4], bh[4], bl[4];
            const int kb = s * 4 + lk;
#pragma unroll
            for (int i = 0; i < 4; ++i) {
                int ca = kb * 128 + wm * 64 + i * 16 + l15;
                ah[i] = *(const bf16x8*)&AsH[(size_t)ca * 8];
                al[i] = *(const bf16x8*)&AsL[(size_t)ca * 8];
                int cb = kb * 128 + wn * 64 + i * 16 + l15;
                bh[i] = *(const bf16x8*)&BsH[(size_t)cb * 8];
                bl[i] = *(const bf16x8*)&BsL[(size_t)cb * 8];
            }
#pragma unroll
            for (int i = 0; i < 4; ++i)
#pragma unroll
                for (int j = 0; j < 4; ++j) {
                    acc[i][j] = __builtin_amdgcn_mfma_f32_16x16x32_bf16(ah[i], bh[j], acc[i][j], 0, 0, 0);
                    acc[i][j] = __builtin_amdgcn_mfma_f32_16x16x32_bf16(ah[i], bl[j], acc[i][j], 0, 0, 0);
                    acc[i][j] = __builtin_amdgcn_mfma_f32_16x16x32_bf16(al[i], bh[j], acc[i][j], 0, 0, 0);
                }
        }
    }

    // epilogue: C/D frag layout (verified): col = lane&15, row = (lane>>4)*4 + reg
#pragma unroll
    for (int i = 0; i < 4; ++i) {
        int row0 = bm + wm * 64 + i * 16 + lk * 4;
#pragma unroll
        for (int j = 0; j < 4; ++j) {
            int col = bn + wn * 64 + j * 16 + l15;
            float bz = bias[col];
#pragma unroll
            for (int r = 0; r < 4; ++r) {
                int row = row0 + r;
                float v = acc[i][j][r] + bz;
                if (MODE == 0) {
                    Cf[(size_t)row * N + col] = v;
                } else {
                    v = fmaxf(v, 0.f);
                    ushort_t hh, ll; split2(v, hh, ll);
                    Ch[(size_t)row * N + col] = hh;
                    Cl[(size_t)row * N + col] = ll;
                }
            }
        }
    }
}

// ---------------------------------------------------------------------------
// Elementwise
// ---------------------------------------------------------------------------

__global__ void enc_pre0_kernel(const float* __restrict__ inp, const float* __restrict__ w,
                                const float* __restrict__ b, ushort_t* __restrict__ oh,
                                ushort_t* __restrict__ ol, int t) {
    int idx = blockIdx.x * blockDim.x + threadIdx.x;
    if (idx >= MPAD * H) return;
    int r = idx >> 8, h = idx & 255;
    float v = 0.f;
    if (r < ROWS) {
        int bb = r / NNODE, n = r % NNODE;
        const float* ip = inp + (((size_t)bb * T_HIST + t) * NNODE + n) * 2;
        v = fmaxf(ip[0] * w[h] + ip[1] * w[H + h] + b[h], 0.f);
    }
    ushort_t hh, ll; split2(v, hh, ll);
    oh[idx] = hh; ol[idx] = ll;
}

__global__ void dec_pre0_kernel(const float* __restrict__ y, const float* __restrict__ w,
                                const float* __restrict__ b, ushort_t* __restrict__ oh,
                                ushort_t* __restrict__ ol) {
    int idx = blockIdx.x * blockDim.x + threadIdx.x;
    if (idx >= MPAD * H) return;
    int r = idx >> 8, h = idx & 255;
    float v = fmaxf(y[r] * w[h] + b[h], 0.f);
    ushort_t hh, ll; split2(v, hh, ll);
    oh[idx] = hh; ol[idx] = ll;
}

// gates [MPAD,4H] (i,f,g,o); c fp32 in/out; h out as bf16 pair
__global__ void lstm_cell_kernel(const float* __restrict__ gates,
                                 ushort_t* __restrict__ hh_, ushort_t* __restrict__ hl_,
                                 float* __restrict__ c) {
    int idx = blockIdx.x * blockDim.x + threadIdx.x;
    if (idx >= MPAD * H) return;
    int r = idx >> 8, j = idx & 255;
    const float* g = gates + (size_t)r * G4 + j;
    float ig = g[0], fg = g[H], gg = g[2 * H], og = g[3 * H];
    float si = 1.f / (1.f + expf(-ig));
    float sf = 1.f / (1.f + expf(-fg));
    float so = 1.f / (1.f + expf(-og));
    float tg = tanhf(gg);
    float cn = sf * c[idx] + si * tg;
    float hn = so * tanhf(cn);
    c[idx] = cn;
    ushort_t hh, ll; split2(hn, hh, ll);
    hh_[idx] = hh; hl_[idx] = ll;
}

__global__ void proj_kernel(const ushort_t* __restrict__ xh, const ushort_t* __restrict__ xl,
                            const float* __restrict__ pw, const float* __restrict__ pb,
                            float* __restrict__ y, float* __restrict__ out, int t) {
    int wid = threadIdx.x >> 6, lane = threadIdx.x & 63;
    int r = blockIdx.x * 4 + wid;
    if (r >= ROWS) return;
    const ushort_t* xhr = xh + (size_t)r * H;
    const ushort_t* xlr = xl + (size_t)r * H;
    float s = 0.f;
#pragma unroll
    for (int i = 0; i < H / 64; ++i) {
        int ii = lane + i * 64;
        s += (bf2f(xhr[ii]) + bf2f(xlr[ii])) * pw[ii];
    }
#pragma unroll
    for (int off = 32; off > 0; off >>= 1) s += __shfl_down(s, off, 64);
    if (lane == 0) {
        float v = s + pb[0];
        y[r] = v;
        int bb = r / NNODE, n = r % NNODE;
        out[((size_t)bb * T_PRED + t) * NNODE + n] = v;
    }
}

// ---------------------------------------------------------------------------
// Launch
// ---------------------------------------------------------------------------
static inline void gemm_big(const ushort_t* a1h, const ushort_t* a1l,
                            const ushort_t* a2h, const ushort_t* a2l,
                            const ushort_t* bh, const ushort_t* bl, const float* bias,
                            float* gates, hipStream_t s) {
    gemm_bf16s_kernel<0><<<(MPAD / 128) * 8, 256, 0, s>>>(
        a1h, a1l, a2h, a2l, 256, bh, bl, bias, gates, nullptr, nullptr, G4, 512, 8, 1);
}
static inline void gemm_small(const ushort_t* ah, const ushort_t* al,
                              const ushort_t* bh, const ushort_t* bl, const float* bias,
                              ushort_t* ch, ushort_t* cl, hipStream_t s) {
    gemm_bf16s_kernel<1><<<(MPAD / 128) * 2, 256, 0, s>>>(
        ah, al, nullptr, nullptr, 256, bh, bl, bias, nullptr, ch, cl, H, 256, 2, 0);
}

extern "C" void kernel_launch(void* const* d_in, const int* in_sizes, int n_in,
                              void* d_out, int out_size, void* d_ws, size_t ws_size,
                              hipStream_t stream) {
    (void)in_sizes; (void)n_in; (void)out_size; (void)ws_size;

    const float* inputs      = (const float*)d_in[0];
    // d_in[1..7]: adaptive-supports MLP — dead code (returns identity), skipped.
    const float* enc_pre_w0  = (const float*)d_in[8];
    const float* enc_pre_b0  = (const float*)d_in[9];
    const float* enc_pre_w1  = (const float*)d_in[10];
    const float* enc_pre_b1  = (const float*)d_in[11];
    const float* enc_wih     = (const float*)d_in[12];
    const float* enc_whh     = (const float*)d_in[13];
    const float* enc_bih     = (const float*)d_in[14];
    const float* enc_bhh     = (const float*)d_in[15];
    const float* dec_pre_w0  = (const float*)d_in[16];
    const float* dec_pre_b0  = (const float*)d_in[17];
    const float* dec_pre_w1  = (const float*)d_in[18];
    const float* dec_pre_b1  = (const float*)d_in[19];
    const float* dec_wih     = (const float*)d_in[20];
    const float* dec_whh     = (const float*)d_in[21];
    const float* dec_bih     = (const float*)d_in[22];
    const float* dec_bhh     = (const float*)d_in[23];
    const float* dec_post_w0 = (const float*)d_in[24];
    const float* dec_post_b0 = (const float*)d_in[25];
    const float* dec_post_w1 = (const float*)d_in[26];
    const float* dec_post_b1 = (const float*)d_in[27];
    const float* proj_w      = (const float*)d_in[28];
    const float* proj_b      = (const float*)d_in[29];
    float* out = (float*)d_out;

    // ---- workspace layout ----
    char* wsb = (char*)d_ws;
    size_t off = 0;
    auto allocF = [&](size_t n) { float* p = (float*)(wsb + off); off += n * 4; return p; };
    auto allocU = [&](size_t n) { ushort_t* p = (ushort_t*)(wsb + off); off += ((n * 2 + 15) & ~(size_t)15); return p; };

    // packed weights (bf16 hi/lo)
    ushort_t* encB0H = allocU((size_t)512 * G4); ushort_t* encB0L = allocU((size_t)512 * G4);
    ushort_t* encB1H = allocU((size_t)512 * G4); ushort_t* encB1L = allocU((size_t)512 * G4);
    ushort_t* decB0H = allocU((size_t)512 * G4); ushort_t* decB0L = allocU((size_t)512 * G4);
    ushort_t* decB1H = allocU((size_t)512 * G4); ushort_t* decB1L = allocU((size_t)512 * G4);
    ushort_t* encW1H = allocU((size_t)H * H);    ushort_t* encW1L = allocU((size_t)H * H);
    ushort_t* decP1H = allocU((size_t)H * H);    ushort_t* decP1L = allocU((size_t)H * H);
    ushort_t* dpo0H  = allocU((size_t)H * H);    ushort_t* dpo0L  = allocU((size_t)H * H);
    ushort_t* dpo1H  = allocU((size_t)H * H);    ushort_t* dpo1L  = allocU((size_t)H * H);
    // fp32 small weights / biases
    float* encW0eff   = allocF(2 * H);
    float* decPre0eff = allocF(H);
    float* encBias0 = allocF(G4); float* encBias1 = allocF(G4);
    float* decBias0 = allocF(G4); float* decBias1 = allocF(G4);
    // states / activations
    ushort_t* h0h = allocU((size_t)MPAD * H); ushort_t* h0l = allocU((size_t)MPAD * H);
    ushort_t* h1h = allocU((size_t)MPAD * H); ushort_t* h1l = allocU((size_t)MPAD * H);
    float* c0 = allocF((size_t)MPAD * H);
    float* c1 = allocF((size_t)MPAD * H);
    ushort_t* xah = allocU((size_t)MPAD * H); ushort_t* xal = allocU((size_t)MPAD * H);
    ushort_t* xbh = allocU((size_t)MPAD * H); ushort_t* xbl = allocU((size_t)MPAD * H);
    float* gates = allocF((size_t)MPAD * G4);
    float* y = allocF(MPAD);

    const int EW = 256;
    const size_t LOFF = (size_t)G4 * H;

    // ---- weight prep ----
    pack_big_kernel<<<(64 * G4) / EW, EW, 0, stream>>>(enc_wih,        enc_whh,        encB0H, encB0L);
    pack_big_kernel<<<(64 * G4) / EW, EW, 0, stream>>>(enc_wih + LOFF, enc_whh + LOFF, encB1H, encB1L);
    pack_big_kernel<<<(64 * G4) / EW, EW, 0, stream>>>(dec_wih,        dec_whh,        decB0H, decB0L);
    pack_big_kernel<<<(64 * G4) / EW, EW, 0, stream>>>(dec_wih + LOFF, dec_whh + LOFF, decB1H, decB1L);
    pack_small_kernel<<<(32 * H) / EW, EW, 0, stream>>>(enc_pre_w1,  encW1H, encW1L);
    pack_small_kernel<<<(32 * H) / EW, EW, 0, stream>>>(dec_pre_w1,  decP1H, decP1L);
    pack_small_kernel<<<(32 * H) / EW, EW, 0, stream>>>(dec_post_w0, dpo0H,  dpo0L);
    pack_small_kernel<<<(32 * H) / EW, EW, 0, stream>>>(dec_post_w1, dpo1H,  dpo1L);
    collapse_kernel<<<(2 * H + EW - 1) / EW, EW, 0, stream>>>(enc_pre_w0, encW0eff, 2, 5);
    collapse_kernel<<<(H + EW - 1) / EW, EW, 0, stream>>>(dec_pre_w0, decPre0eff, 1, 5);
    add_vec_kernel<<<(G4 + EW - 1) / EW, EW, 0, stream>>>(enc_bih,      enc_bhh,      encBias0, G4);
    add_vec_kernel<<<(G4 + EW - 1) / EW, EW, 0, stream>>>(enc_bih + G4, enc_bhh + G4, encBias1, G4);
    add_vec_kernel<<<(G4 + EW - 1) / EW, EW, 0, stream>>>(dec_bih,      dec_bhh,      decBias0, G4);
    add_vec_kernel<<<(G4 + EW - 1) / EW, EW, 0, stream>>>(dec_bih + G4, dec_bhh + G4, decBias1, G4);

    // ---- init state ----
    hipMemsetAsync(h0h, 0, (size_t)MPAD * H * 2, stream);
    hipMemsetAsync(h0l, 0, (size_t)MPAD * H * 2, stream);
    hipMemsetAsync(h1h, 0, (size_t)MPAD * H * 2, stream);
    hipMemsetAsync(h1l, 0, (size_t)MPAD * H * 2, stream);
    hipMemsetAsync(c0, 0, (size_t)MPAD * H * 4, stream);
    hipMemsetAsync(c1, 0, (size_t)MPAD * H * 4, stream);
    hipMemsetAsync(y, 0, (size_t)MPAD * 4, stream);

    const int EB = (MPAD * H) / EW;

    // ---- encoder ----
    for (int t = 0; t < T_HIST; ++t) {
        enc_pre0_kernel<<<EB, EW, 0, stream>>>(inputs, encW0eff, enc_pre_b0, xah, xal, t);
        gemm_small(xah, xal, encW1H, encW1L, enc_pre_b1, xbh, xbl, stream);
        gemm_big(xbh, xbl, h0h, h0l, encB0H, encB0L, encBias0, gates, stream);
        lstm_cell_kernel<<<EB, EW, 0, stream>>>(gates, h0h, h0l, c0);
        gemm_big(h0h, h0l, h1h, h1l, encB1H, encB1L, encBias1, gates, stream);
        lstm_cell_kernel<<<EB, EW, 0, stream>>>(gates, h1h, h1l, c1);
    }

    // ---- decoder ----
    for (int t = 0; t < T_PRED; ++t) {
        dec_pre0_kernel<<<EB, EW, 0, stream>>>(y, decPre0eff, dec_pre_b0, xah, xal);
        gemm_small(xah, xal, decP1H, decP1L, dec_pre_b1, xbh, xbl, stream);
        gemm_big(xbh, xbl, h0h, h0l, decB0H, decB0L, decBias0, gates, stream);
        lstm_cell_kernel<<<EB, EW, 0, stream>>>(gates, h0h, h0l, c0);
        gemm_big(h0h, h0l, h1h, h1l, decB1H, decB1L, decBias1, gates, stream);
        lstm_cell_kernel<<<EB, EW, 0, stream>>>(gates, h1h, h1l, c1);
        gemm_small(h1h, h1l, dpo0H, dpo0L, dec_post_b0, xah, xal, stream);
        gemm_small(xah, xal, dpo1H, dpo1L, dec_post_b1, xbh, xbl, stream);
        proj_kernel<<<(ROWS + 3) / 4, 256, 0, stream>>>(xbh, xbl, proj_w, proj_b, y, out, t);
    }
}

// Round 3
// 3470.256 us; speedup vs baseline: 2.6477x; 1.1798x over previous
//
#include <hip/hip_runtime.h>
#include <math.h>

#define BATCH 32
#define NNODE 325
#define T_HIST 12
#define T_PRED 12
#define H 256
#define G4 1024
#define ROWS (BATCH*NNODE)
#define MPAD 10496  // 82*128

typedef __attribute__((ext_vector_type(8))) short bf16x8;
typedef __attribute__((ext_vector_type(4))) float f32x4;
typedef unsigned short ushort_t;
typedef unsigned int uint_t;

#define GLL16(gp, sp) __builtin_amdgcn_global_load_lds( \
    (const __attribute__((address_space(1))) void*)(gp), \
    (__attribute__((address_space(3))) void*)(sp), 16, 0, 0)

__device__ inline float bf2f(ushort_t u) { return __uint_as_float(((uint_t)u) << 16); }

__device__ inline void split2(float v, ushort_t& h, ushort_t& l) {
    uint_t b = __float_as_uint(v);
    uint_t hb = (b + 0x7fffu + ((b >> 16) & 1u)) & 0xffff0000u;
    h = (ushort_t)(hb >> 16);
    float r = v - __uint_as_float(hb);
    uint_t rb = __float_as_uint(r);
    l = (ushort_t)((rb + 0x7fffu + ((rb >> 16) & 1u)) >> 16);
}

__device__ inline float sigm(float x) {
    x = fminf(fmaxf(x, -30.f), 30.f);
    return 1.f / (1.f + __expf(-x));
}
__device__ inline float tanh_f(float x) {
    x = fminf(fmaxf(x, -15.f), 15.f);
    float e = __expf(2.f * x);
    return (e - 1.f) / (e + 1.f);
}

// ---------------------------------------------------------------------------
// Weight prep
// ---------------------------------------------------------------------------
__global__ void collapse_kernel(const float* __restrict__ w, float* __restrict__ out,
                                int cin, int nblk) {
    int idx = blockIdx.x * blockDim.x + threadIdx.x;
    if (idx >= cin * H) return;
    int c = idx / H, h = idx % H;
    float s = 0.f;
    for (int k = 0; k < nblk; ++k) s += w[(size_t)(k * cin + c) * H + h];
    out[idx] = s;
}

// Gate-interleaved big pack: col' = 4*j + gate. Bxh/Bxl from wih, Bhh/Bhl from whh.
// Layout [32 kg][1024 col'][8]. biasI[col'] = bih[gcol]+bhh[gcol].
__global__ void pack_big_kernel(const float* __restrict__ wih, const float* __restrict__ whh,
                                const float* __restrict__ bih, const float* __restrict__ bhh,
                                ushort_t* __restrict__ Bxh, ushort_t* __restrict__ Bxl,
                                ushort_t* __restrict__ Bhh, ushort_t* __restrict__ Bhl,
                                float* __restrict__ biasI) {
    int idx = blockIdx.x * blockDim.x + threadIdx.x;  // 32*1024
    if (idx >= 32 * G4) return;
    int kg = idx >> 10, col = idx & 1023;
    int j = col >> 2, g = col & 3;
    int gcol = g * 256 + j;
    if (kg == 0) biasI[col] = bih[gcol] + bhh[gcol];
#pragma unroll
    for (int jj = 0; jj < 8; ++jj) {
        int k = kg * 8 + jj;
        ushort_t hh, ll;
        split2(wih[(size_t)gcol * H + k], hh, ll);
        Bxh[(size_t)idx * 8 + jj] = hh; Bxl[(size_t)idx * 8 + jj] = ll;
        split2(whh[(size_t)gcol * H + k], hh, ll);
        Bhh[(size_t)idx * 8 + jj] = hh; Bhl[(size_t)idx * 8 + jj] = ll;
    }
}

// Small pack: collapse 5 K-blocks, layout [32 kg][256 n][8] hi/lo.
__global__ void pack_small_kernel(const float* __restrict__ w,
                                  ushort_t* __restrict__ Bh, ushort_t* __restrict__ Bl) {
    int idx = blockIdx.x * blockDim.x + threadIdx.x;  // 32*256
    if (idx >= 32 * H) return;
    int kg = idx >> 8, n = idx & 255;
#pragma unroll
    for (int jj = 0; jj < 8; ++jj) {
        int k = kg * 8 + jj;
        float s = 0.f;
        for (int blk = 0; blk < 5; ++blk) s += w[(size_t)(blk * H + k) * H + n];
        ushort_t hh, ll; split2(s, hh, ll);
        Bh[(size_t)idx * 8 + jj] = hh; Bl[(size_t)idx * 8 + jj] = ll;
    }
}

// ---------------------------------------------------------------------------
// Producers writing k-packed [kg][MPAD][8] hi/lo
// ---------------------------------------------------------------------------
__global__ void enc_pre0_pk(const float* __restrict__ inp, const float* __restrict__ w,
                            const float* __restrict__ b, ushort_t* __restrict__ oh,
                            ushort_t* __restrict__ ol, int t) {
    int m = blockIdx.x * 256 + threadIdx.x;   // grid (41, 32)
    int kg = blockIdx.y;
    float ip0 = 0.f, ip1 = 0.f;
    if (m < ROWS) {
        int bb = m / NNODE, nn = m % NNODE;
        const float* ip = inp + (((size_t)bb * T_HIST + t) * NNODE + nn) * 2;
        ip0 = ip[0]; ip1 = ip[1];
    }
    union { ushort_t u[8]; bf16x8 v; } hc, lc;
#pragma unroll
    for (int jj = 0; jj < 8; ++jj) {
        int j = kg * 8 + jj;
        float v = (m < ROWS) ? fmaxf(ip0 * w[j] + ip1 * w[H + j] + b[j], 0.f) : 0.f;
        split2(v, hc.u[jj], lc.u[jj]);
    }
    size_t base = ((size_t)kg * MPAD + m) * 8;
    *(bf16x8*)&oh[base] = hc.v;
    *(bf16x8*)&ol[base] = lc.v;
}

__global__ void dec_pre0_pk(const float* __restrict__ y, const float* __restrict__ w,
                            const float* __restrict__ b, ushort_t* __restrict__ oh,
                            ushort_t* __restrict__ ol) {
    int m = blockIdx.x * 256 + threadIdx.x;   // grid (41, 32)
    int kg = blockIdx.y;
    float yv = y[m];
    union { ushort_t u[8]; bf16x8 v; } hc, lc;
#pragma unroll
    for (int jj = 0; jj < 8; ++jj) {
        int j = kg * 8 + jj;
        float v = fmaxf(yv * w[j] + b[j], 0.f);
        split2(v, hc.u[jj], lc.u[jj]);
    }
    size_t base = ((size_t)kg * MPAD + m) * 8;
    *(bf16x8*)&oh[base] = hc.v;
    *(bf16x8*)&ol[base] = lc.v;
}

// ---------------------------------------------------------------------------
// K'-expanded split-bf16 GEMM, 128x128 tile, BK=64 chunks, static pass schedule.
// Pass structure per group g (3 passes): [AH.BH][AH.BL][AL.BH], chunks double-buffered.
// GATES: fused LSTM cell epilogue (gate-interleaved cols), writes h k-packed + c.
// !GATES: relu + split, writes k-packed via shfl-xor pairing.
// ---------------------------------------------------------------------------
template<int NP> struct Sched;
template<> struct Sched<24> {
    static constexpr signed char aseg[24] = {-1,1,0, -1,1,0, -1,1,0, -1,1,2, -1,3,2, -1,3,2, -1,3,2, -1,3,-1};
    static constexpr signed char ack [24] = { 0,0,1,  0,1,2,  0,2,3,  0,3,0,  0,0,1,  0,1,2,  0,2,3,  0,3,0};
    static constexpr signed char bseg[24] = { 1,-1,0, 1,-1,0, 1,-1,0, 1,-1,2, 3,-1,2, 3,-1,2, 3,-1,2, 3,-1,-1};
    static constexpr signed char bck [24] = { 0,0,1,  1,0,2,  2,0,3,  3,0,0,  0,0,1,  1,0,2,  2,0,3,  3,0,0};
};
template<> struct Sched<12> {
    static constexpr signed char aseg[12] = {-1,1,0, -1,1,0, -1,1,0, -1,1,-1};
    static constexpr signed char ack [12] = { 0,0,1,  0,1,2,  0,2,3,  0,3,0};
    static constexpr signed char bseg[12] = { 1,-1,0, 1,-1,0, 1,-1,0, 1,-1,-1};
    static constexpr signed char bck [12] = { 0,0,1,  1,0,2,  2,0,3,  3,0,0};
};

template<bool GATES, int NPASS, int NB>
__global__ __launch_bounds__(256, 2) void gemm_k(
    const ushort_t* __restrict__ A0p, const ushort_t* __restrict__ A1p,
    const ushort_t* __restrict__ A2p, const ushort_t* __restrict__ A3p,
    int astride,
    const ushort_t* __restrict__ B0p, const ushort_t* __restrict__ B1p,
    const ushort_t* __restrict__ B2p, const ushort_t* __restrict__ B3p,
    const float* __restrict__ bias,
    float* __restrict__ cst,
    ushort_t* __restrict__ OH, ushort_t* __restrict__ OL,
    int ostride, int nbx, int doSwz)
{
    __shared__ __align__(16) ushort_t As[2][8192];
    __shared__ __align__(16) ushort_t Bs[2][8192];

    int bid = blockIdx.x;
    if (doSwz) { int cpx = gridDim.x >> 3; bid = (bid & 7) * cpx + (bid >> 3); }
    const int bm = (bid / nbx) * 128, bn = (bid % nbx) * 128;
    const int tid = threadIdx.x, lane = tid & 63, wid = tid >> 6;
    const int wm = wid >> 1, wn = wid & 1;
    const int l15 = lane & 15, lk = lane >> 4;

    const ushort_t* Aseg[4] = {A0p, A1p, A2p, A3p};
    const ushort_t* Bseg[4] = {B0p, B1p, B2p, B3p};

    auto stageA = [&](const ushort_t* src, int ck, ushort_t* dst) {
#pragma unroll
        for (int i = 0; i < 4; ++i) {
            int u = wid * 256 + i * 64;
            int ul = u + lane;
            int kgl = ul >> 7, m = ul & 127;
            GLL16(src + ((size_t)(ck * 8 + kgl) * astride + bm + m) * 8, dst + (size_t)u * 8);
        }
    };
    auto stageB = [&](const ushort_t* src, int ck, ushort_t* dst) {
#pragma unroll
        for (int i = 0; i < 4; ++i) {
            int u = wid * 256 + i * 64;
            int ul = u + lane;
            int kgl = ul >> 7, n = ul & 127;
            GLL16(src + ((size_t)(ck * 8 + kgl) * NB + bn + n) * 8, dst + (size_t)u * 8);
        }
    };

    f32x4 acc[4][4] = {};

    // prologue: first AH/BH chunks
    stageA(Aseg[0], 0, &As[0][0]);
    stageB(Bseg[0], 0, &Bs[0][0]);
    __syncthreads();

#pragma unroll
    for (int p = 0; p < NPASS; ++p) {
        constexpr auto& sa = Sched<NPASS>::aseg;
        constexpr auto& sac = Sched<NPASS>::ack;
        constexpr auto& sb = Sched<NPASS>::bseg;
        constexpr auto& sbc = Sched<NPASS>::bck;
        if (sa[p] >= 0) stageA(Aseg[sa[p]], sac[p], &As[(p % 3 == 1) ? 1 : 0][0]);
        if (sb[p] >= 0) stageB(Bseg[sb[p]], sbc[p], &Bs[(p & 1) ^ 1][0]);
        const ushort_t* ab = &As[(p % 3 == 2) ? 1 : 0][0];
        const ushort_t* bb = &Bs[p & 1][0];
#pragma unroll
        for (int si = 0; si < 2; ++si) {
            bf16x8 af[4], bf[4];
            const int kb = si * 4 + lk;
#pragma unroll
            for (int i = 0; i < 4; ++i) {
                af[i] = *(const bf16x8*)&ab[(size_t)(kb * 128 + wm * 64 + i * 16 + l15) * 8];
                bf[i] = *(const bf16x8*)&bb[(size_t)(kb * 128 + wn * 64 + i * 16 + l15) * 8];
            }
#pragma unroll
            for (int i = 0; i < 4; ++i)
#pragma unroll
                for (int j = 0; j < 4; ++j)
                    acc[i][j] = __builtin_amdgcn_mfma_f32_16x16x32_bf16(bf[j], af[i], acc[i][j], 0, 0, 0);
        }
        __syncthreads();
    }

    // ---- epilogue ----
    // swapped operands: acc[i][jj][r] = C[m][n], m = bm+wm*64+i*16+l15, n = bn+wn*64+jj*16+lk*4+r
    if constexpr (GATES) {
        uint_t* Hs = (uint_t*)&As[0][0];   // 128*36*4 = 18.4KB, staging dead
        const int jbase = (bn >> 2) + wn * 16;
#pragma unroll
        for (int jj = 0; jj < 4; ++jj) {
            float4 b4 = *(const float4*)&bias[bn + wn * 64 + jj * 16 + lk * 4];
            int j = jbase + jj * 4 + lk;
#pragma unroll
            for (int i = 0; i < 4; ++i) {
                int m = bm + wm * 64 + i * 16 + l15;
                float vi = acc[i][jj][0] + b4.x;
                float vf = acc[i][jj][1] + b4.y;
                float vg = acc[i][jj][2] + b4.z;
                float vo = acc[i][jj][3] + b4.w;
                float cold = cst[(size_t)j * MPAD + m];
                float cn = sigm(vf) * cold + sigm(vi) * tanh_f(vg);
                float hn = sigm(vo) * tanh_f(cn);
                cst[(size_t)j * MPAD + m] = cn;
                ushort_t hh, hl; split2(hn, hh, hl);
                Hs[(wm * 64 + i * 16 + l15) * 36 + wn * 16 + jj * 4 + lk] = ((uint_t)hh << 16) | hl;
            }
        }
        __syncthreads();
#pragma unroll
        for (int it = 0; it < 2; ++it) {
            int u = tid + it * 256;
            int mloc = u & 127, kgl = u >> 7;
            uint4 w0 = *(const uint4*)&Hs[mloc * 36 + kgl * 8];
            uint4 w1 = *(const uint4*)&Hs[mloc * 36 + kgl * 8 + 4];
            union { uint_t u2[4]; bf16x8 v; } hi, lo;
            hi.u2[0] = (w0.x >> 16) | (w0.y & 0xffff0000u);
            hi.u2[1] = (w0.z >> 16) | (w0.w & 0xffff0000u);
            hi.u2[2] = (w1.x >> 16) | (w1.y & 0xffff0000u);
            hi.u2[3] = (w1.z >> 16) | (w1.w & 0xffff0000u);
            lo.u2[0] = (w0.x & 0xffffu) | (w0.y << 16);
            lo.u2[1] = (w0.z & 0xffffu) | (w0.w << 16);
            lo.u2[2] = (w1.x & 0xffffu) | (w1.y << 16);
            lo.u2[3] = (w1.z & 0xffffu) | (w1.w << 16);
            size_t base = ((size_t)((bn >> 5) + kgl) * ostride + bm + mloc) * 8;
            *(bf16x8*)&OH[base] = hi.v;
            *(bf16x8*)&OL[base] = lo.v;
        }
    } else {
#pragma unroll
        for (int jj = 0; jj < 4; ++jj) {
            float4 b4 = *(const float4*)&bias[bn + wn * 64 + jj * 16 + lk * 4];
#pragma unroll
            for (int i = 0; i < 4; ++i) {
                float v0 = fmaxf(acc[i][jj][0] + b4.x, 0.f);
                float v1 = fmaxf(acc[i][jj][1] + b4.y, 0.f);
                float v2 = fmaxf(acc[i][jj][2] + b4.z, 0.f);
                float v3 = fmaxf(acc[i][jj][3] + b4.w, 0.f);
                ushort_t h0, h1, h2, h3, l0, l1, l2, l3;
                split2(v0, h0, l0); split2(v1, h1, l1);
                split2(v2, h2, l2); split2(v3, h3, l3);
                uint_t hu0 = (uint_t)h0 | ((uint_t)h1 << 16), hu1 = (uint_t)h2 | ((uint_t)h3 << 16);
                uint_t lu0 = (uint_t)l0 | ((uint_t)l1 << 16), lu1 = (uint_t)l2 | ((uint_t)l3 << 16);
                uint_t ph0 = (uint_t)__shfl_xor((int)hu0, 16, 64);
                uint_t ph1 = (uint_t)__shfl_xor((int)hu1, 16, 64);
                uint_t pl0 = (uint_t)__shfl_xor((int)lu0, 16, 64);
                uint_t pl1 = (uint_t)__shfl_xor((int)lu1, 16, 64);
                int kgg = ((bn + wn * 64 + jj * 16) >> 3) + (lk >> 1);
                size_t base = ((size_t)kgg * ostride + bm + wm * 64 + i * 16 + l15) * 8;
                union { uint_t u2[4]; bf16x8 v; } ch;
                if ((lk & 1) == 0) {
                    ch.u2[0] = hu0; ch.u2[1] = hu1; ch.u2[2] = ph0; ch.u2[3] = ph1;
                    *(bf16x8*)&OH[base] = ch.v;
                } else {
                    ch.u2[0] = pl0; ch.u2[1] = pl1; ch.u2[2] = lu0; ch.u2[3] = lu1;
                    *(bf16x8*)&OL[base] = ch.v;
                }
            }
        }
    }
}

// ---------------------------------------------------------------------------
// Projection: y[r] = sum_k (xh+xl)[r,k]*pw[k] + pb ; scatter to out.
// x is k-packed [32][MPAD][8].
// ---------------------------------------------------------------------------
__global__ void proj_kernel(const ushort_t* __restrict__ xh, const ushort_t* __restrict__ xl,
                            const float* __restrict__ pw, const float* __restrict__ pb,
                            float* __restrict__ y, float* __restrict__ out, int t) {
    int wid = threadIdx.x >> 6, lane = threadIdx.x & 63;
    int r = blockIdx.x * 4 + wid;
    if (r >= ROWS) return;
    const int kg = lane >> 1, sub = (lane & 1) * 4;
    size_t base = ((size_t)kg * MPAD + r) * 8 + sub;
    float s = 0.f;
#pragma unroll
    for (int q = 0; q < 4; ++q) {
        int k = kg * 8 + sub + q;
        s += (bf2f(xh[base + q]) + bf2f(xl[base + q])) * pw[k];
    }
#pragma unroll
    for (int off = 32; off > 0; off >>= 1) s += __shfl_down(s, off, 64);
    if (lane == 0) {
        float v = s + pb[0];
        y[r] = v;
        int bb = r / NNODE, n = r % NNODE;
        out[((size_t)bb * T_PRED + t) * NNODE + n] = v;
    }
}

// ---------------------------------------------------------------------------
extern "C" void kernel_launch(void* const* d_in, const int* in_sizes, int n_in,
                              void* d_out, int out_size, void* d_ws, size_t ws_size,
                              hipStream_t stream) {
    (void)in_sizes; (void)n_in; (void)out_size; (void)ws_size;

    const float* inputs      = (const float*)d_in[0];
    // d_in[1..7]: adaptive-supports MLP — dead code (returns identity), skipped.
    const float* enc_pre_w0  = (const float*)d_in[8];
    const float* enc_pre_b0  = (const float*)d_in[9];
    const float* enc_pre_w1  = (const float*)d_in[10];
    const float* enc_pre_b1  = (const float*)d_in[11];
    const float* enc_wih     = (const float*)d_in[12];
    const float* enc_whh     = (const float*)d_in[13];
    const float* enc_bih     = (const float*)d_in[14];
    const float* enc_bhh     = (const float*)d_in[15];
    const float* dec_pre_w0  = (const float*)d_in[16];
    const float* dec_pre_b0  = (const float*)d_in[17];
    const float* dec_pre_w1  = (const float*)d_in[18];
    const float* dec_pre_b1  = (const float*)d_in[19];
    const float* dec_wih     = (const float*)d_in[20];
    const float* dec_whh     = (const float*)d_in[21];
    const float* dec_bih     = (const float*)d_in[22];
    const float* dec_bhh     = (const float*)d_in[23];
    const float* dec_post_w0 = (const float*)d_in[24];
    const float* dec_post_b0 = (const float*)d_in[25];
    const float* dec_post_w1 = (const float*)d_in[26];
    const float* dec_post_b1 = (const float*)d_in[27];
    const float* proj_w      = (const float*)d_in[28];
    const float* proj_b      = (const float*)d_in[29];
    float* out = (float*)d_out;

    char* wsb = (char*)d_ws;
    size_t off = 0;
    auto allocF = [&](size_t n) { float* p = (float*)(wsb + off); off += ((n * 4 + 15) & ~(size_t)15); return p; };
    auto allocU = [&](size_t n) { ushort_t* p = (ushort_t*)(wsb + off); off += ((n * 2 + 15) & ~(size_t)15); return p; };

    const size_t BIGW = (size_t)32 * G4 * 8;   // per big-pack array
    const size_t SMLW = (size_t)32 * H * 8;
    const size_t ACT  = (size_t)32 * MPAD * 8; // k-packed activation

    // big weight packs: [layer-gemm][4 arrays: xh,xl,hh,hl]
    ushort_t* eB0[4]; ushort_t* eB1[4]; ushort_t* dB0[4]; ushort_t* dB1[4];
    for (int q = 0; q < 4; ++q) eB0[q] = allocU(BIGW);
    for (int q = 0; q < 4; ++q) eB1[q] = allocU(BIGW);
    for (int q = 0; q < 4; ++q) dB0[q] = allocU(BIGW);
    for (int q = 0; q < 4; ++q) dB1[q] = allocU(BIGW);
    float* eBI0 = allocF(G4); float* eBI1 = allocF(G4);
    float* dBI0 = allocF(G4); float* dBI1 = allocF(G4);
    // small packs
    ushort_t* eP1h = allocU(SMLW); ushort_t* eP1l = allocU(SMLW);
    ushort_t* dP1h = allocU(SMLW); ushort_t* dP1l = allocU(SMLW);
    ushort_t* po0h = allocU(SMLW); ushort_t* po0l = allocU(SMLW);
    ushort_t* po1h = allocU(SMLW); ushort_t* po1l = allocU(SMLW);
    float* encW0eff = allocF(2 * H);
    float* decPre0eff = allocF(H);
    // states (double-buffered h per layer)
    ushort_t* h0H[2]; ushort_t* h0L[2]; ushort_t* h1H[2]; ushort_t* h1L[2];
    for (int q = 0; q < 2; ++q) { h0H[q] = allocU(ACT); h0L[q] = allocU(ACT); }
    for (int q = 0; q < 2; ++q) { h1H[q] = allocU(ACT); h1L[q] = allocU(ACT); }
    float* c0 = allocF((size_t)H * MPAD);
    float* c1 = allocF((size_t)H * MPAD);
    ushort_t* xaH = allocU(ACT); ushort_t* xaL = allocU(ACT);
    ushort_t* xbH = allocU(ACT); ushort_t* xbL = allocU(ACT);
    float* y = allocF(MPAD);

    const size_t LOFF = (size_t)G4 * H;
    const int EW = 256;

    // ---- weight prep ----
    pack_big_kernel<<<128, EW, 0, stream>>>(enc_wih, enc_whh, enc_bih, enc_bhh,
                                            eB0[0], eB0[1], eB0[2], eB0[3], eBI0);
    pack_big_kernel<<<128, EW, 0, stream>>>(enc_wih + LOFF, enc_whh + LOFF, enc_bih + G4, enc_bhh + G4,
                                            eB1[0], eB1[1], eB1[2], eB1[3], eBI1);
    pack_big_kernel<<<128, EW, 0, stream>>>(dec_wih, dec_whh, dec_bih, dec_bhh,
                                            dB0[0], dB0[1], dB0[2], dB0[3], dBI0);
    pack_big_kernel<<<128, EW, 0, stream>>>(dec_wih + LOFF, dec_whh + LOFF, dec_bih + G4, dec_bhh + G4,
                                            dB1[0], dB1[1], dB1[2], dB1[3], dBI1);
    pack_small_kernel<<<32, EW, 0, stream>>>(enc_pre_w1, eP1h, eP1l);
    pack_small_kernel<<<32, EW, 0, stream>>>(dec_pre_w1, dP1h, dP1l);
    pack_small_kernel<<<32, EW, 0, stream>>>(dec_post_w0, po0h, po0l);
    pack_small_kernel<<<32, EW, 0, stream>>>(dec_post_w1, po1h, po1l);
    collapse_kernel<<<2, EW, 0, stream>>>(enc_pre_w0, encW0eff, 2, 5);
    collapse_kernel<<<1, EW, 0, stream>>>(dec_pre_w0, decPre0eff, 1, 5);

    // ---- init state ----
    for (int q = 0; q < 2; ++q) {
        hipMemsetAsync(h0H[q], 0, ACT * 2, stream); hipMemsetAsync(h0L[q], 0, ACT * 2, stream);
        hipMemsetAsync(h1H[q], 0, ACT * 2, stream); hipMemsetAsync(h1L[q], 0, ACT * 2, stream);
    }
    hipMemsetAsync(c0, 0, (size_t)H * MPAD * 4, stream);
    hipMemsetAsync(c1, 0, (size_t)H * MPAD * 4, stream);
    hipMemsetAsync(y, 0, (size_t)MPAD * 4, stream);

    const dim3 PG(MPAD / 256, 32);

    // ---- encoder ----
    for (int t = 0; t < T_HIST; ++t) {
        int pr = t & 1;
        enc_pre0_pk<<<PG, EW, 0, stream>>>(inputs, encW0eff, enc_pre_b0, xaH, xaL, t);
        gemm_k<false, 12, 256><<<164, EW, 0, stream>>>(
            xaH, xaL, nullptr, nullptr, MPAD, eP1h, eP1l, nullptr, nullptr,
            enc_pre_b1, nullptr, xbH, xbL, MPAD, 2, 0);
        gemm_k<true, 24, 1024><<<656, EW, 0, stream>>>(
            xbH, xbL, h0H[pr], h0L[pr], MPAD, eB0[0], eB0[1], eB0[2], eB0[3],
            eBI0, c0, h0H[pr ^ 1], h0L[pr ^ 1], MPAD, 8, 1);
        gemm_k<true, 24, 1024><<<656, EW, 0, stream>>>(
            h0H[pr ^ 1], h0L[pr ^ 1], h1H[pr], h1L[pr], MPAD, eB1[0], eB1[1], eB1[2], eB1[3],
            eBI1, c1, h1H[pr ^ 1], h1L[pr ^ 1], MPAD, 8, 1);
    }

    // ---- decoder ----
    for (int d = 0; d < T_PRED; ++d) {
        int pr = d & 1;
        dec_pre0_pk<<<PG, EW, 0, stream>>>(y, decPre0eff, dec_pre_b0, xaH, xaL);
        gemm_k<false, 12, 256><<<164, EW, 0, stream>>>(
            xaH, xaL, nullptr, nullptr, MPAD, dP1h, dP1l, nullptr, nullptr,
            dec_pre_b1, nullptr, xbH, xbL, MPAD, 2, 0);
        gemm_k<true, 24, 1024><<<656, EW, 0, stream>>>(
            xbH, xbL, h0H[pr], h0L[pr], MPAD, dB0[0], dB0[1], dB0[2], dB0[3],
            dBI0, c0, h0H[pr ^ 1], h0L[pr ^ 1], MPAD, 8, 1);
        gemm_k<true, 24, 1024><<<656, EW, 0, stream>>>(
            h0H[pr ^ 1], h0L[pr ^ 1], h1H[pr], h1L[pr], MPAD, dB1[0], dB1[1], dB1[2], dB1[3],
            dBI1, c1, h1H[pr ^ 1], h1L[pr ^ 1], MPAD, 8, 1);
        gemm_k<false, 12, 256><<<164, EW, 0, stream>>>(
            h1H[pr ^ 1], h1L[pr ^ 1], nullptr, nullptr, MPAD, po0h, po0l, nullptr, nullptr,
            dec_post_b0, nullptr, xaH, xaL, MPAD, 2, 0);
        gemm_k<false, 12, 256><<<164, EW, 0, stream>>>(
            xaH, xaL, nullptr, nullptr, MPAD, po1h, po1l, nullptr, nullptr,
            dec_post_b1, nullptr, xbH, xbL, MPAD, 2, 0);
        proj_kernel<<<(ROWS + 3) / 4, EW, 0, stream>>>(xbH, xbL, proj_w, proj_b, y, out, d);
    }
}

// Round 4
// 2600.903 us; speedup vs baseline: 3.5327x; 1.3343x over previous
//
#include <hip/hip_runtime.h>
#include <math.h>

#define BATCH 32
#define NNODE 325
#define T_HIST 12
#define T_PRED 12
#define H 256
#define G4 1024
#define ROWS (BATCH*NNODE)
#define MPAD 10496  // 82*128

typedef __attribute__((ext_vector_type(8))) short bf16x8;
typedef __attribute__((ext_vector_type(4))) float f32x4;
typedef unsigned short ushort_t;
typedef unsigned int uint_t;

#define GLL16(gp, sp) __builtin_amdgcn_global_load_lds( \
    (const __attribute__((address_space(1))) void*)(gp), \
    (__attribute__((address_space(3))) void*)(sp), 16, 0, 0)

__device__ inline float bf2f(ushort_t u) { return __uint_as_float(((uint_t)u) << 16); }

__device__ inline void split2(float v, ushort_t& h, ushort_t& l) {
    uint_t b = __float_as_uint(v);
    uint_t hb = (b + 0x7fffu + ((b >> 16) & 1u)) & 0xffff0000u;
    h = (ushort_t)(hb >> 16);
    float r = v - __uint_as_float(hb);
    uint_t rb = __float_as_uint(r);
    l = (ushort_t)((rb + 0x7fffu + ((rb >> 16) & 1u)) >> 16);
}

__device__ inline float sigm(float x) {
    x = fminf(fmaxf(x, -30.f), 30.f);
    return 1.f / (1.f + __expf(-x));
}
__device__ inline float tanh_f(float x) {
    x = fminf(fmaxf(x, -15.f), 15.f);
    float e = __expf(2.f * x);
    return (e - 1.f) / (e + 1.f);
}

// ---------------------------------------------------------------------------
// Weight prep
// ---------------------------------------------------------------------------
__global__ void collapse_kernel(const float* __restrict__ w, float* __restrict__ out,
                                int cin, int nblk) {
    int idx = blockIdx.x * blockDim.x + threadIdx.x;
    if (idx >= cin * H) return;
    int c = idx / H, h = idx % H;
    float s = 0.f;
    for (int k = 0; k < nblk; ++k) s += w[(size_t)(k * cin + c) * H + h];
    out[idx] = s;
}

// Gate-interleaved big pack: col' = 4*j + gate. Layout [32 kg][1024 col'][8].
__global__ void pack_big_kernel(const float* __restrict__ wih, const float* __restrict__ whh,
                                const float* __restrict__ bih, const float* __restrict__ bhh,
                                ushort_t* __restrict__ Bxh, ushort_t* __restrict__ Bxl,
                                ushort_t* __restrict__ Bhh, ushort_t* __restrict__ Bhl,
                                float* __restrict__ biasI) {
    int idx = blockIdx.x * blockDim.x + threadIdx.x;  // 32*1024
    if (idx >= 32 * G4) return;
    int kg = idx >> 10, col = idx & 1023;
    int j = col >> 2, g = col & 3;
    int gcol = g * 256 + j;
    if (kg == 0) biasI[col] = bih[gcol] + bhh[gcol];
#pragma unroll
    for (int jj = 0; jj < 8; ++jj) {
        int k = kg * 8 + jj;
        ushort_t hh, ll;
        split2(wih[(size_t)gcol * H + k], hh, ll);
        Bxh[(size_t)idx * 8 + jj] = hh; Bxl[(size_t)idx * 8 + jj] = ll;
        split2(whh[(size_t)gcol * H + k], hh, ll);
        Bhh[(size_t)idx * 8 + jj] = hh; Bhl[(size_t)idx * 8 + jj] = ll;
    }
}

// Small pack: collapse 5 K-blocks, layout [32 kg][256 n][8] hi/lo.
__global__ void pack_small_kernel(const float* __restrict__ w,
                                  ushort_t* __restrict__ Bh, ushort_t* __restrict__ Bl) {
    int idx = blockIdx.x * blockDim.x + threadIdx.x;  // 32*256
    if (idx >= 32 * H) return;
    int kg = idx >> 8, n = idx & 255;
#pragma unroll
    for (int jj = 0; jj < 8; ++jj) {
        int k = kg * 8 + jj;
        float s = 0.f;
        for (int blk = 0; blk < 5; ++blk) s += w[(size_t)(blk * H + k) * H + n];
        ushort_t hh, ll; split2(s, hh, ll);
        Bh[(size_t)idx * 8 + jj] = hh; Bl[(size_t)idx * 8 + jj] = ll;
    }
}

// ---------------------------------------------------------------------------
// Producers writing k-packed [kg][MPAD][8] hi/lo
// ---------------------------------------------------------------------------
__global__ void enc_pre0_pk(const float* __restrict__ inp, const float* __restrict__ w,
                            const float* __restrict__ b, ushort_t* __restrict__ oh,
                            ushort_t* __restrict__ ol, int t) {
    int m = blockIdx.x * 256 + threadIdx.x;   // grid (41, 32)
    int kg = blockIdx.y;
    float ip0 = 0.f, ip1 = 0.f;
    if (m < ROWS) {
        int bb = m / NNODE, nn = m % NNODE;
        const float* ip = inp + (((size_t)bb * T_HIST + t) * NNODE + nn) * 2;
        ip0 = ip[0]; ip1 = ip[1];
    }
    union { ushort_t u[8]; bf16x8 v; } hc, lc;
#pragma unroll
    for (int jj = 0; jj < 8; ++jj) {
        int j = kg * 8 + jj;
        float v = (m < ROWS) ? fmaxf(ip0 * w[j] + ip1 * w[H + j] + b[j], 0.f) : 0.f;
        split2(v, hc.u[jj], lc.u[jj]);
    }
    size_t base = ((size_t)kg * MPAD + m) * 8;
    *(bf16x8*)&oh[base] = hc.v;
    *(bf16x8*)&ol[base] = lc.v;
}

__global__ void dec_pre0_pk(const float* __restrict__ y, const float* __restrict__ w,
                            const float* __restrict__ b, ushort_t* __restrict__ oh,
                            ushort_t* __restrict__ ol) {
    int m = blockIdx.x * 256 + threadIdx.x;   // grid (41, 32)
    int kg = blockIdx.y;
    float yv = y[m];
    union { ushort_t u[8]; bf16x8 v; } hc, lc;
#pragma unroll
    for (int jj = 0; jj < 8; ++jj) {
        int j = kg * 8 + jj;
        float v = fmaxf(yv * w[j] + b[j], 0.f);
        split2(v, hc.u[jj], lc.u[jj]);
    }
    size_t base = ((size_t)kg * MPAD + m) * 8;
    *(bf16x8*)&oh[base] = hc.v;
    *(bf16x8*)&ol[base] = lc.v;
}

// ---------------------------------------------------------------------------
// Super-chunk pipelined split-bf16 GEMM. 128x128 tile, k-slab 32 per SC.
// Each SC stages AH/AL/BH/BL (4x8KB) into a 2-slot LDS ring with raw
// s_barrier + counted vmcnt (no drain); one set of 16 ds_read_b128 feeds
// all 3 split-term MFMA groups (48 MFMA / SC / wave).
// GATES: fused LSTM cell epilogue; !GATES: relu+split k-packed output.
// ---------------------------------------------------------------------------
template<bool GATES, int NSC, int HSC, int NB>
__global__ __launch_bounds__(256, 2) void gemm_k(
    const ushort_t* __restrict__ AxH, const ushort_t* __restrict__ AxL,
    const ushort_t* __restrict__ AhH, const ushort_t* __restrict__ AhL,
    int astrideX, int arowX, int astrideH,
    const ushort_t* __restrict__ BxH, const ushort_t* __restrict__ BxL,
    const ushort_t* __restrict__ BhH, const ushort_t* __restrict__ BhL,
    const float* __restrict__ bias, float* __restrict__ cst,
    ushort_t* __restrict__ OH, ushort_t* __restrict__ OL,
    int ostride, int nbx, int doSwz)
{
    __shared__ __align__(16) ushort_t As[2][2][4096];   // [slot][hi/lo][8KB]
    __shared__ __align__(16) ushort_t Bs[2][2][4096];

    int bid = blockIdx.x;
    if (doSwz) { int cpx = gridDim.x >> 3; bid = (bid & 7) * cpx + (bid >> 3); }
    const int bm = (bid / nbx) * 128, bn = (bid % nbx) * 128;
    const int tid = threadIdx.x, lane = tid & 63, wid = tid >> 6;
    const int wm = wid >> 1, wn = wid & 1;
    const int l15 = lane & 15, lk = lane >> 4;

    auto stageSC = [&](int s, int slot) {
        const ushort_t *Ah, *Al, *Bh, *Bl; int ck, astr, abase;
        if (s < HSC) { Ah = AxH; Al = AxL; Bh = BxH; Bl = BxL; ck = s; astr = astrideX; abase = arowX; }
        else         { Ah = AhH; Al = AhL; Bh = BhH; Bl = BhL; ck = s - HSC; astr = astrideH; abase = 0; }
#pragma unroll
        for (int q = 0; q < 2; ++q) {
            int ubase = (tid & 192) + q * 256;   // wave-uniform unit base
            int u = ubase + lane;
            int kgl = u >> 7, rc = u & 127;
            size_t ga = ((size_t)(ck * 4 + kgl) * astr + abase + bm + rc) * 8;
            size_t gb = ((size_t)(ck * 4 + kgl) * NB + bn + rc) * 8;
            GLL16(Ah + ga, &As[slot][0][ubase * 8]);
            GLL16(Al + ga, &As[slot][1][ubase * 8]);
            GLL16(Bh + gb, &Bs[slot][0][ubase * 8]);
            GLL16(Bl + gb, &Bs[slot][1][ubase * 8]);
        }
    };

    f32x4 acc[4][4] = {};

    stageSC(0, 0);   // prologue: 8 gll/thread outstanding

#pragma unroll
    for (int s = 0; s < NSC; ++s) {
        // barrier #1: all waves finished compute(s-1) -> slot[(s+1)&1] free
        __builtin_amdgcn_s_barrier();
        if (s + 1 < NSC) {
            stageSC(s + 1, (s + 1) & 1);
            asm volatile("s_waitcnt vmcnt(8)" ::: "memory");  // SC(s) landed; SC(s+1) in flight
        } else {
            asm volatile("s_waitcnt vmcnt(0)" ::: "memory");
        }
        // barrier #2: everyone's SC(s) loads landed
        __builtin_amdgcn_s_barrier();
        __builtin_amdgcn_sched_barrier(0);

        const int slot = s & 1;
        bf16x8 ah[4], al[4], bh[4], bl[4];
#pragma unroll
        for (int i = 0; i < 4; ++i) {
            int ea = (lk * 128 + wm * 64 + i * 16 + l15) * 8;
            ah[i] = *(const bf16x8*)&As[slot][0][ea];
            al[i] = *(const bf16x8*)&As[slot][1][ea];
            int eb = (lk * 128 + wn * 64 + i * 16 + l15) * 8;
            bh[i] = *(const bf16x8*)&Bs[slot][0][eb];
            bl[i] = *(const bf16x8*)&Bs[slot][1][eb];
        }
#pragma unroll
        for (int i = 0; i < 4; ++i)
#pragma unroll
            for (int j = 0; j < 4; ++j)
                acc[i][j] = __builtin_amdgcn_mfma_f32_16x16x32_bf16(bh[j], ah[i], acc[i][j], 0, 0, 0);
#pragma unroll
        for (int i = 0; i < 4; ++i)
#pragma unroll
            for (int j = 0; j < 4; ++j)
                acc[i][j] = __builtin_amdgcn_mfma_f32_16x16x32_bf16(bl[j], ah[i], acc[i][j], 0, 0, 0);
#pragma unroll
        for (int i = 0; i < 4; ++i)
#pragma unroll
            for (int j = 0; j < 4; ++j)
                acc[i][j] = __builtin_amdgcn_mfma_f32_16x16x32_bf16(bh[j], al[i], acc[i][j], 0, 0, 0);
    }

    // ---- epilogue ----
    // swapped operands: acc[i][jj][r] = C[m][n], m = bm+wm*64+i*16+l15, n = bn+wn*64+jj*16+lk*4+r
    if constexpr (GATES) {
        uint_t* Hs = (uint_t*)(&As[0][0][0]);   // 128*36*4B = 18.4KB, staging dead
        const int jbase = (bn >> 2) + wn * 16;
#pragma unroll
        for (int jj = 0; jj < 4; ++jj) {
            float4 b4 = *(const float4*)&bias[bn + wn * 64 + jj * 16 + lk * 4];
            int j = jbase + jj * 4 + lk;
#pragma unroll
            for (int i = 0; i < 4; ++i) {
                int m = bm + wm * 64 + i * 16 + l15;
                float vi = acc[i][jj][0] + b4.x;
                float vf = acc[i][jj][1] + b4.y;
                float vg = acc[i][jj][2] + b4.z;
                float vo = acc[i][jj][3] + b4.w;
                float cold = cst[(size_t)j * MPAD + m];
                float cn = sigm(vf) * cold + sigm(vi) * tanh_f(vg);
                float hn = sigm(vo) * tanh_f(cn);
                cst[(size_t)j * MPAD + m] = cn;
                ushort_t hh, hl; split2(hn, hh, hl);
                Hs[(wm * 64 + i * 16 + l15) * 36 + wn * 16 + jj * 4 + lk] = ((uint_t)hh << 16) | hl;
            }
        }
        __syncthreads();
#pragma unroll
        for (int it = 0; it < 2; ++it) {
            int u = tid + it * 256;
            int mloc = u & 127, kgl = u >> 7;
            uint4 w0 = *(const uint4*)&Hs[mloc * 36 + kgl * 8];
            uint4 w1 = *(const uint4*)&Hs[mloc * 36 + kgl * 8 + 4];
            union { uint_t u2[4]; bf16x8 v; } hi, lo;
            hi.u2[0] = (w0.x >> 16) | (w0.y & 0xffff0000u);
            hi.u2[1] = (w0.z >> 16) | (w0.w & 0xffff0000u);
            hi.u2[2] = (w1.x >> 16) | (w1.y & 0xffff0000u);
            hi.u2[3] = (w1.z >> 16) | (w1.w & 0xffff0000u);
            lo.u2[0] = (w0.x & 0xffffu) | (w0.y << 16);
            lo.u2[1] = (w0.z & 0xffffu) | (w0.w << 16);
            lo.u2[2] = (w1.x & 0xffffu) | (w1.y << 16);
            lo.u2[3] = (w1.z & 0xffffu) | (w1.w << 16);
            size_t base = ((size_t)((bn >> 5) + kgl) * ostride + bm + mloc) * 8;
            *(bf16x8*)&OH[base] = hi.v;
            *(bf16x8*)&OL[base] = lo.v;
        }
    } else {
#pragma unroll
        for (int jj = 0; jj < 4; ++jj) {
            float4 b4 = *(const float4*)&bias[bn + wn * 64 + jj * 16 + lk * 4];
#pragma unroll
            for (int i = 0; i < 4; ++i) {
                float v0 = fmaxf(acc[i][jj][0] + b4.x, 0.f);
                float v1 = fmaxf(acc[i][jj][1] + b4.y, 0.f);
                float v2 = fmaxf(acc[i][jj][2] + b4.z, 0.f);
                float v3 = fmaxf(acc[i][jj][3] + b4.w, 0.f);
                ushort_t h0, h1, h2, h3, l0, l1, l2, l3;
                split2(v0, h0, l0); split2(v1, h1, l1);
                split2(v2, h2, l2); split2(v3, h3, l3);
                uint_t hu0 = (uint_t)h0 | ((uint_t)h1 << 16), hu1 = (uint_t)h2 | ((uint_t)h3 << 16);
                uint_t lu0 = (uint_t)l0 | ((uint_t)l1 << 16), lu1 = (uint_t)l2 | ((uint_t)l3 << 16);
                uint_t ph0 = (uint_t)__shfl_xor((int)hu0, 16, 64);
                uint_t ph1 = (uint_t)__shfl_xor((int)hu1, 16, 64);
                uint_t pl0 = (uint_t)__shfl_xor((int)lu0, 16, 64);
                uint_t pl1 = (uint_t)__shfl_xor((int)lu1, 16, 64);
                int kgg = ((bn + wn * 64 + jj * 16) >> 3) + (lk >> 1);
                size_t base = ((size_t)kgg * ostride + bm + wm * 64 + i * 16 + l15) * 8;
                union { uint_t u2[4]; bf16x8 v; } ch;
                if ((lk & 1) == 0) {
                    ch.u2[0] = hu0; ch.u2[1] = hu1; ch.u2[2] = ph0; ch.u2[3] = ph1;
                    *(bf16x8*)&OH[base] = ch.v;
                } else {
                    ch.u2[0] = pl0; ch.u2[1] = pl1; ch.u2[2] = lu0; ch.u2[3] = lu1;
                    *(bf16x8*)&OL[base] = ch.v;
                }
            }
        }
    }
}

// ---------------------------------------------------------------------------
// Projection: y[r] = sum_k (xh+xl)[r,k]*pw[k] + pb ; scatter to out.
// ---------------------------------------------------------------------------
__global__ void proj_kernel(const ushort_t* __restrict__ xh, const ushort_t* __restrict__ xl,
                            const float* __restrict__ pw, const float* __restrict__ pb,
                            float* __restrict__ y, float* __restrict__ out, int t) {
    int wid = threadIdx.x >> 6, lane = threadIdx.x & 63;
    int r = blockIdx.x * 4 + wid;
    if (r >= ROWS) return;
    const int kg = lane >> 1, sub = (lane & 1) * 4;
    size_t base = ((size_t)kg * MPAD + r) * 8 + sub;
    float s = 0.f;
#pragma unroll
    for (int q = 0; q < 4; ++q) {
        int k = kg * 8 + sub + q;
        s += (bf2f(xh[base + q]) + bf2f(xl[base + q])) * pw[k];
    }
#pragma unroll
    for (int off = 32; off > 0; off >>= 1) s += __shfl_down(s, off, 64);
    if (lane == 0) {
        float v = s + pb[0];
        y[r] = v;
        int bb = r / NNODE, n = r % NNODE;
        out[((size_t)bb * T_PRED + t) * NNODE + n] = v;
    }
}

// ---------------------------------------------------------------------------
static inline void gemm_big(const ushort_t* xH, const ushort_t* xL,
                            const ushort_t* hH, const ushort_t* hL,
                            ushort_t* const* B, const float* bias, float* c,
                            ushort_t* oH, ushort_t* oL, hipStream_t s) {
    gemm_k<true, 16, 8, 1024><<<656, 256, 0, s>>>(
        xH, xL, hH, hL, MPAD, 0, MPAD,
        B[0], B[1], B[2], B[3], bias, c, oH, oL, MPAD, 8, 1);
}
static inline void gemm_small(const ushort_t* aH, const ushort_t* aL,
                              const ushort_t* bH, const ushort_t* bL, const float* bias,
                              ushort_t* oH, ushort_t* oL, hipStream_t s) {
    gemm_k<false, 8, 8, 256><<<164, 256, 0, s>>>(
        aH, aL, nullptr, nullptr, MPAD, 0, MPAD,
        bH, bL, nullptr, nullptr, bias, nullptr, oH, oL, MPAD, 2, 0);
}

extern "C" void kernel_launch(void* const* d_in, const int* in_sizes, int n_in,
                              void* d_out, int out_size, void* d_ws, size_t ws_size,
                              hipStream_t stream) {
    (void)in_sizes; (void)n_in; (void)out_size; (void)ws_size;

    const float* inputs      = (const float*)d_in[0];
    // d_in[1..7]: adaptive-supports MLP — dead code (returns identity), skipped.
    const float* enc_pre_w0  = (const float*)d_in[8];
    const float* enc_pre_b0  = (const float*)d_in[9];
    const float* enc_pre_w1  = (const float*)d_in[10];
    const float* enc_pre_b1  = (const float*)d_in[11];
    const float* enc_wih     = (const float*)d_in[12];
    const float* enc_whh     = (const float*)d_in[13];
    const float* enc_bih     = (const float*)d_in[14];
    const float* enc_bhh     = (const float*)d_in[15];
    const float* dec_pre_w0  = (const float*)d_in[16];
    const float* dec_pre_b0  = (const float*)d_in[17];
    const float* dec_pre_w1  = (const float*)d_in[18];
    const float* dec_pre_b1  = (const float*)d_in[19];
    const float* dec_wih     = (const float*)d_in[20];
    const float* dec_whh     = (const float*)d_in[21];
    const float* dec_bih     = (const float*)d_in[22];
    const float* dec_bhh     = (const float*)d_in[23];
    const float* dec_post_w0 = (const float*)d_in[24];
    const float* dec_post_b0 = (const float*)d_in[25];
    const float* dec_post_w1 = (const float*)d_in[26];
    const float* dec_post_b1 = (const float*)d_in[27];
    const float* proj_w      = (const float*)d_in[28];
    const float* proj_b      = (const float*)d_in[29];
    float* out = (float*)d_out;

    char* wsb = (char*)d_ws;
    size_t off = 0;
    auto allocF = [&](size_t n) { float* p = (float*)(wsb + off); off += ((n * 4 + 15) & ~(size_t)15); return p; };
    auto allocU = [&](size_t n) { ushort_t* p = (ushort_t*)(wsb + off); off += ((n * 2 + 15) & ~(size_t)15); return p; };

    const size_t BIGW = (size_t)32 * G4 * 8;
    const size_t SMLW = (size_t)32 * H * 8;
    const size_t ACT  = (size_t)32 * MPAD * 8;

    ushort_t* eB0[4]; ushort_t* eB1[4]; ushort_t* dB0[4]; ushort_t* dB1[4];
    for (int q = 0; q < 4; ++q) eB0[q] = allocU(BIGW);
    for (int q = 0; q < 4; ++q) eB1[q] = allocU(BIGW);
    for (int q = 0; q < 4; ++q) dB0[q] = allocU(BIGW);
    for (int q = 0; q < 4; ++q) dB1[q] = allocU(BIGW);
    float* eBI0 = allocF(G4); float* eBI1 = allocF(G4);
    float* dBI0 = allocF(G4); float* dBI1 = allocF(G4);
    ushort_t* eP1h = allocU(SMLW); ushort_t* eP1l = allocU(SMLW);
    ushort_t* dP1h = allocU(SMLW); ushort_t* dP1l = allocU(SMLW);
    ushort_t* po0h = allocU(SMLW); ushort_t* po0l = allocU(SMLW);
    ushort_t* po1h = allocU(SMLW); ushort_t* po1l = allocU(SMLW);
    float* encW0eff = allocF(2 * H);
    float* decPre0eff = allocF(H);
    ushort_t* h0H[2]; ushort_t* h0L[2]; ushort_t* h1H[2]; ushort_t* h1L[2];
    for (int q = 0; q < 2; ++q) { h0H[q] = allocU(ACT); h0L[q] = allocU(ACT); }
    for (int q = 0; q < 2; ++q) { h1H[q] = allocU(ACT); h1L[q] = allocU(ACT); }
    float* c0 = allocF((size_t)H * MPAD);
    float* c1 = allocF((size_t)H * MPAD);
    ushort_t* xaH = allocU(ACT); ushort_t* xaL = allocU(ACT);
    ushort_t* xbH = allocU(ACT); ushort_t* xbL = allocU(ACT);
    float* y = allocF(MPAD);

    const size_t LOFF = (size_t)G4 * H;
    const int EW = 256;

    // ---- weight prep ----
    pack_big_kernel<<<128, EW, 0, stream>>>(enc_wih, enc_whh, enc_bih, enc_bhh,
                                            eB0[0], eB0[1], eB0[2], eB0[3], eBI0);
    pack_big_kernel<<<128, EW, 0, stream>>>(enc_wih + LOFF, enc_whh + LOFF, enc_bih + G4, enc_bhh + G4,
                                            eB1[0], eB1[1], eB1[2], eB1[3], eBI1);
    pack_big_kernel<<<128, EW, 0, stream>>>(dec_wih, dec_whh, dec_bih, dec_bhh,
                                            dB0[0], dB0[1], dB0[2], dB0[3], dBI0);
    pack_big_kernel<<<128, EW, 0, stream>>>(dec_wih + LOFF, dec_whh + LOFF, dec_bih + G4, dec_bhh + G4,
                                            dB1[0], dB1[1], dB1[2], dB1[3], dBI1);
    pack_small_kernel<<<32, EW, 0, stream>>>(enc_pre_w1, eP1h, eP1l);
    pack_small_kernel<<<32, EW, 0, stream>>>(dec_pre_w1, dP1h, dP1l);
    pack_small_kernel<<<32, EW, 0, stream>>>(dec_post_w0, po0h, po0l);
    pack_small_kernel<<<32, EW, 0, stream>>>(dec_post_w1, po1h, po1l);
    collapse_kernel<<<2, EW, 0, stream>>>(enc_pre_w0, encW0eff, 2, 5);
    collapse_kernel<<<1, EW, 0, stream>>>(dec_pre_w0, decPre0eff, 1, 5);

    // ---- init state ----
    for (int q = 0; q < 2; ++q) {
        hipMemsetAsync(h0H[q], 0, ACT * 2, stream); hipMemsetAsync(h0L[q], 0, ACT * 2, stream);
        hipMemsetAsync(h1H[q], 0, ACT * 2, stream); hipMemsetAsync(h1L[q], 0, ACT * 2, stream);
    }
    hipMemsetAsync(c0, 0, (size_t)H * MPAD * 4, stream);
    hipMemsetAsync(c1, 0, (size_t)H * MPAD * 4, stream);
    hipMemsetAsync(y, 0, (size_t)MPAD * 4, stream);

    const dim3 PG(MPAD / 256, 32);

    // ---- encoder ----
    for (int t = 0; t < T_HIST; ++t) {
        int pr = t & 1;
        enc_pre0_pk<<<PG, EW, 0, stream>>>(inputs, encW0eff, enc_pre_b0, xaH, xaL, t);
        gemm_small(xaH, xaL, eP1h, eP1l, enc_pre_b1, xbH, xbL, stream);
        gemm_big(xbH, xbL, h0H[pr], h0L[pr], eB0, eBI0, c0, h0H[pr ^ 1], h0L[pr ^ 1], stream);
        gemm_big(h0H[pr ^ 1], h0L[pr ^ 1], h1H[pr], h1L[pr], eB1, eBI1, c1, h1H[pr ^ 1], h1L[pr ^ 1], stream);
    }

    // ---- decoder ----
    for (int d = 0; d < T_PRED; ++d) {
        int pr = d & 1;
        dec_pre0_pk<<<PG, EW, 0, stream>>>(y, decPre0eff, dec_pre_b0, xaH, xaL);
        gemm_small(xaH, xaL, dP1h, dP1l, dec_pre_b1, xbH, xbL, stream);
        gemm_big(xbH, xbL, h0H[pr], h0L[pr], dB0, dBI0, c0, h0H[pr ^ 1], h0L[pr ^ 1], stream);
        gemm_big(h0H[pr ^ 1], h0L[pr ^ 1], h1H[pr], h1L[pr], dB1, dBI1, c1, h1H[pr ^ 1], h1L[pr ^ 1], stream);
        gemm_small(h1H[pr ^ 1], h1L[pr ^ 1], po0h, po0l, dec_post_b0, xaH, xaL, stream);
        gemm_small(xaH, xaL, po1h, po1l, dec_post_b1, xbH, xbL, stream);
        proj_kernel<<<(ROWS + 3) / 4, EW, 0, stream>>>(xbH, xbL, proj_w, proj_b, y, out, d);
    }
}